// Round 5
// baseline (238.162 us; speedup 1.0000x reference)
//
#include <hip/hip_runtime.h>
#include <hip/hip_cooperative_groups.h>

namespace cg = cooperative_groups;

// B=D=H=512. Inputs fp32: x, W1, b1, W2, b2, w3, b3.
// d_out = out[512] ++ gram[512,512] (fp32).
// G = 1 + H2H2^T + (1+H1H1^T)⊙(G2G2^T) + (1+XX^T)⊙(G1G1^T)
//   g2 = w3⊙1{z2>0};  g1 = (W2 g2)⊙1{z1>0}
// Single cooperative kernel, 5 stages separated by grid.sync():
//   0: split/transposes   1: fwd1 (split-bf16 MFMA)   2: fwd2 (+out GEMV)
//   3: g1 = mask⊙(G2@W2^T)   4: 5 fused bf16 syrks -> gram
// 256 blocks x 256 threads = 1 block/CU (co-resident by cooperative launch).

#define NN 512

typedef __attribute__((ext_vector_type(8))) short v8s;
typedef __attribute__((ext_vector_type(4))) float v4f;

static __device__ __forceinline__ unsigned short f2bf(float f) {
    union { float f; unsigned u; } v; v.f = f;
    unsigned r = v.u + 0x7FFF + ((v.u >> 16) & 1);
    return (unsigned short)(r >> 16);
}
static __device__ __forceinline__ float bf2f(unsigned short h) {
    union { unsigned u; float f; } v; v.u = ((unsigned)h) << 16;
    return v.f;
}

__global__ __launch_bounds__(256, 1) void fused(
    const float* __restrict__ x, const float* __restrict__ W1,
    const float* __restrict__ b1, const float* __restrict__ W2,
    const float* __restrict__ b2, const float* __restrict__ w3,
    const float* __restrict__ b3, float* __restrict__ out,
    float* __restrict__ gram, unsigned short* __restrict__ ws) {
    unsigned short* xhi  = ws;
    unsigned short* xlo  = xhi  + NN * NN;
    unsigned short* W1th = xlo  + NN * NN;
    unsigned short* W1tl = W1th + NN * NN;
    unsigned short* W2th = W1tl + NN * NN;
    unsigned short* W2tl = W2th + NN * NN;
    unsigned short* W2b  = W2tl + NN * NN;
    unsigned short* H1b  = W2b  + NN * NN;
    unsigned short* H1lo = H1b  + NN * NN;
    unsigned short* H2b  = H1lo + NN * NN;
    unsigned short* G2b  = H2b  + NN * NN;
    unsigned short* G1b  = G2b  + NN * NN;

    cg::grid_group grid = cg::this_grid();
    __shared__ float T[32][33];

    const int t = threadIdx.x;
    const int blk = blockIdx.x;
    const int bx = blk & 15, by = blk >> 4;
    const int r0 = by * 32, c0 = bx * 32;

    // ================= stage 0: conversions =================
    {
        const int lr = t >> 3, lc = (t & 7) * 4;
        // x hi/lo split (straight layout)
        float4 v = *(const float4*)&x[(r0 + lr) * NN + c0 + lc];
        ushort4 hi, lo;
        hi.x = f2bf(v.x); lo.x = f2bf(v.x - bf2f(hi.x));
        hi.y = f2bf(v.y); lo.y = f2bf(v.y - bf2f(hi.y));
        hi.z = f2bf(v.z); lo.z = f2bf(v.z - bf2f(hi.z));
        hi.w = f2bf(v.w); lo.w = f2bf(v.w - bf2f(hi.w));
        *(ushort4*)&xhi[(r0 + lr) * NN + c0 + lc] = hi;
        *(ushort4*)&xlo[(r0 + lr) * NN + c0 + lc] = lo;
        // out init through the coherent point (atomic store, no L2 dirty line)
        if (bx == 0 && t < 32) atomicExch(&out[r0 + t], b3[0]);

        // W1 transpose + split
        float4 w = *(const float4*)&W1[(r0 + lr) * NN + c0 + lc];
        T[lr][lc + 0] = w.x; T[lr][lc + 1] = w.y;
        T[lr][lc + 2] = w.z; T[lr][lc + 3] = w.w;
        __syncthreads();
        {
            float a0 = T[lc + 0][lr], a1 = T[lc + 1][lr];
            float a2 = T[lc + 2][lr], a3 = T[lc + 3][lr];
            ushort4 h4, l4;
            h4.x = f2bf(a0); l4.x = f2bf(a0 - bf2f(h4.x));
            h4.y = f2bf(a1); l4.y = f2bf(a1 - bf2f(h4.y));
            h4.z = f2bf(a2); l4.z = f2bf(a2 - bf2f(h4.z));
            h4.w = f2bf(a3); l4.w = f2bf(a3 - bf2f(h4.w));
            *(ushort4*)&W1th[(c0 + lr) * NN + r0 + lc] = h4;
            *(ushort4*)&W1tl[(c0 + lr) * NN + r0 + lc] = l4;
        }
        __syncthreads();
        // W2 transpose + split + plain bf16 copy
        float4 u = *(const float4*)&W2[(r0 + lr) * NN + c0 + lc];
        ushort4 p4;
        p4.x = f2bf(u.x); p4.y = f2bf(u.y); p4.z = f2bf(u.z); p4.w = f2bf(u.w);
        *(ushort4*)&W2b[(r0 + lr) * NN + c0 + lc] = p4;
        T[lr][lc + 0] = u.x; T[lr][lc + 1] = u.y;
        T[lr][lc + 2] = u.z; T[lr][lc + 3] = u.w;
        __syncthreads();
        {
            float a0 = T[lc + 0][lr], a1 = T[lc + 1][lr];
            float a2 = T[lc + 2][lr], a3 = T[lc + 3][lr];
            ushort4 h4, l4;
            h4.x = f2bf(a0); l4.x = f2bf(a0 - bf2f(h4.x));
            h4.y = f2bf(a1); l4.y = f2bf(a1 - bf2f(h4.y));
            h4.z = f2bf(a2); l4.z = f2bf(a2 - bf2f(h4.z));
            h4.w = f2bf(a3); l4.w = f2bf(a3 - bf2f(h4.w));
            *(ushort4*)&W2th[(c0 + lr) * NN + r0 + lc] = h4;
            *(ushort4*)&W2tl[(c0 + lr) * NN + r0 + lc] = l4;
        }
    }
    grid.sync();

    // wave-level tile coords shared by stages 1-4
    const int wave = t >> 6, lane = t & 63;
    const int r = lane & 15, quad = lane >> 4;
    const int i0 = r0 + 16 * (wave >> 1);
    const int j0 = c0 + 16 * (wave & 1);
    const int ao = (i0 + r) * NN + quad * 8;
    const int bo = (j0 + r) * NN + quad * 8;

    // ================= stage 1: fwd1 =================
    {
        v4f hh = {0.f, 0.f, 0.f, 0.f}, lh = hh, hl = hh;
        #pragma unroll
        for (int k0 = 0; k0 < NN; k0 += 32) {
            v8s ah = *(const v8s*)(xhi  + ao + k0);
            v8s al = *(const v8s*)(xlo  + ao + k0);
            v8s bh = *(const v8s*)(W1th + bo + k0);
            v8s bl = *(const v8s*)(W1tl + bo + k0);
            hh = __builtin_amdgcn_mfma_f32_16x16x32_bf16(ah, bh, hh, 0, 0, 0);
            lh = __builtin_amdgcn_mfma_f32_16x16x32_bf16(al, bh, lh, 0, 0, 0);
            hl = __builtin_amdgcn_mfma_f32_16x16x32_bf16(ah, bl, hl, 0, 0, 0);
        }
        const float bj = b1[j0 + r];
        #pragma unroll
        for (int rr = 0; rr < 4; ++rr) {
            const int i = i0 + quad * 4 + rr, j = j0 + r;
            float zv = (hh[rr] + lh[rr]) + hl[rr] + bj;
            float h = zv > 0.f ? zv : 0.f;
            unsigned short hi = f2bf(h);
            H1b[i * NN + j]  = hi;
            H1lo[i * NN + j] = f2bf(h - bf2f(hi));
        }
    }
    grid.sync();

    // ================= stage 2: fwd2 + out GEMV =================
    {
        v4f hh = {0.f, 0.f, 0.f, 0.f}, lh = hh, hl = hh;
        #pragma unroll
        for (int k0 = 0; k0 < NN; k0 += 32) {
            v8s ah = *(const v8s*)(H1b  + ao + k0);
            v8s al = *(const v8s*)(H1lo + ao + k0);
            v8s bh = *(const v8s*)(W2th + bo + k0);
            v8s bl = *(const v8s*)(W2tl + bo + k0);
            hh = __builtin_amdgcn_mfma_f32_16x16x32_bf16(ah, bh, hh, 0, 0, 0);
            lh = __builtin_amdgcn_mfma_f32_16x16x32_bf16(al, bh, lh, 0, 0, 0);
            hl = __builtin_amdgcn_mfma_f32_16x16x32_bf16(ah, bl, hl, 0, 0, 0);
        }
        const float bj = b2[j0 + r];
        const float wj = w3[j0 + r];
        const unsigned short wjb = f2bf(wj);
        #pragma unroll
        for (int rr = 0; rr < 4; ++rr) {
            const int i = i0 + quad * 4 + rr, j = j0 + r;
            float zv = (hh[rr] + lh[rr]) + hl[rr] + bj;
            float h = zv > 0.f ? zv : 0.f;
            H2b[i * NN + j] = f2bf(h);
            G2b[i * NN + j] = (zv > 0.f) ? wjb : (unsigned short)0;
            float p = h * wj;
            p += __shfl_xor(p, 1, 64);
            p += __shfl_xor(p, 2, 64);
            p += __shfl_xor(p, 4, 64);
            p += __shfl_xor(p, 8, 64);
            if (r == 0) atomicAdd(&out[i], p);
        }
    }
    grid.sync();

    // ================= stage 3: g1 =================
    {
        v4f acc = {0.f, 0.f, 0.f, 0.f};
        #pragma unroll
        for (int k0 = 0; k0 < NN; k0 += 32) {
            v8s a = *(const v8s*)(G2b + ao + k0);
            v8s b = *(const v8s*)(W2b + bo + k0);
            acc = __builtin_amdgcn_mfma_f32_16x16x32_bf16(a, b, acc, 0, 0, 0);
        }
        #pragma unroll
        for (int rr = 0; rr < 4; ++rr) {
            const int i = i0 + quad * 4 + rr;
            const int c = j0 + r;
            // h>=0: bf16(h) != 0 iff h > 0 (denormal cutoff irrelevant here)
            float v = (H1b[i * NN + c] != 0) ? acc[rr] : 0.f;
            G1b[i * NN + c] = f2bf(v);
        }
    }
    grid.sync();

    // ================= stage 4: gram (5 fused syrks) =================
    {
        v4f a0 = {0.f,0.f,0.f,0.f}, a1 = a0, a2 = a0, a3 = a0, a4 = a0;
        #pragma unroll
        for (int k0 = 0; k0 < NN; k0 += 32) {
            v8s xa = *(const v8s*)(xhi + ao + k0), xb2 = *(const v8s*)(xhi + bo + k0);
            v8s ha = *(const v8s*)(H1b + ao + k0), hb  = *(const v8s*)(H1b + bo + k0);
            v8s ga = *(const v8s*)(G1b + ao + k0), gb  = *(const v8s*)(G1b + bo + k0);
            v8s ua = *(const v8s*)(H2b + ao + k0), ub  = *(const v8s*)(H2b + bo + k0);
            v8s va = *(const v8s*)(G2b + ao + k0), vb  = *(const v8s*)(G2b + bo + k0);
            a0 = __builtin_amdgcn_mfma_f32_16x16x32_bf16(xa, xb2, a0, 0, 0, 0);
            a1 = __builtin_amdgcn_mfma_f32_16x16x32_bf16(ha, hb,  a1, 0, 0, 0);
            a2 = __builtin_amdgcn_mfma_f32_16x16x32_bf16(ga, gb,  a2, 0, 0, 0);
            a3 = __builtin_amdgcn_mfma_f32_16x16x32_bf16(ua, ub,  a3, 0, 0, 0);
            a4 = __builtin_amdgcn_mfma_f32_16x16x32_bf16(va, vb,  a4, 0, 0, 0);
        }
        #pragma unroll
        for (int rr = 0; rr < 4; ++rr) {
            const int i = i0 + quad * 4 + rr;
            const int j = j0 + r;
            float g = 1.f + a3[rr] + a4[rr] * (1.f + a1[rr]) + a2[rr] * (1.f + a0[rr]);
            gram[i * NN + j] = g;
        }
    }
}

extern "C" void kernel_launch(void* const* d_in, const int* in_sizes, int n_in,
                              void* d_out, int out_size, void* d_ws, size_t ws_size,
                              hipStream_t stream) {
    const float* x  = (const float*)d_in[0];
    const float* W1 = (const float*)d_in[1];
    const float* b1 = (const float*)d_in[2];
    const float* W2 = (const float*)d_in[3];
    const float* b2 = (const float*)d_in[4];
    const float* w3 = (const float*)d_in[5];
    const float* b3 = (const float*)d_in[6];

    float* out  = (float*)d_out;
    float* gram = out + NN;
    unsigned short* ws = (unsigned short*)d_ws;

    void* kargs[] = {(void*)&x, (void*)&W1, (void*)&b1, (void*)&W2, (void*)&b2,
                     (void*)&w3, (void*)&b3, (void*)&out, (void*)&gram, (void*)&ws};
    hipLaunchCooperativeKernel(reinterpret_cast<void*>(fused), dim3(256),
                               dim3(256), kargs, 0, stream);
}

// Round 6
// 118.163 us; speedup vs baseline: 2.0155x; 2.0155x over previous
//
#include <hip/hip_runtime.h>

// B=D=H=512. Inputs fp32: x, W1, b1, W2, b2, w3, b3.
// d_out = out[512] ++ gram[512,512] (fp32).
// G = 1 + H2H2^T + (1+H1H1^T)⊙(G2G2^T) + (1+XX^T)⊙(G1G1^T)
//   g2 = w3⊙1{z2>0};  g1 = (W2 g2)⊙1{z1>0}
// 5 kernels. MFMA kernels are K-split-4: one 16x16 tile per block, 4 waves
// each accumulate K=128 then LDS-reduce -> grid 1024 blocks = 4 blocks/CU
// = 4 waves/SIMD (latency hiding; R5 showed 1 wave/SIMD = all-stall).

#define NN 512

typedef __attribute__((ext_vector_type(8))) short v8s;
typedef __attribute__((ext_vector_type(4))) float v4f;

static __device__ __forceinline__ unsigned short f2bf(float f) {
    union { float f; unsigned u; } v; v.f = f;
    unsigned r = v.u + 0x7FFF + ((v.u >> 16) & 1);
    return (unsigned short)(r >> 16);
}
static __device__ __forceinline__ float bf2f(unsigned short h) {
    union { unsigned u; float f; } v; v.u = ((unsigned)h) << 16;
    return v.f;
}

// ---- prep: z=0: W1 transpose+split; z=1: W2 transpose+split + plain W2b;
//            z=2: x straight split + out[i]=b3 -----------------------------
__global__ __launch_bounds__(256) void prep(
    const float* __restrict__ x, const float* __restrict__ W1,
    const float* __restrict__ W2, const float* __restrict__ b3,
    unsigned short* __restrict__ xhi, unsigned short* __restrict__ xlo,
    unsigned short* __restrict__ W1th, unsigned short* __restrict__ W1tl,
    unsigned short* __restrict__ W2th, unsigned short* __restrict__ W2tl,
    unsigned short* __restrict__ W2b, float* __restrict__ out) {
    __shared__ float T[32][33];
    const int t = threadIdx.x;
    const int lr = t >> 3, lc = (t & 7) * 4;
    const int r0 = blockIdx.y * 32, c0 = blockIdx.x * 32;
    const int z = blockIdx.z;
    if (z == 2) {
        float4 v = *(const float4*)&x[(r0 + lr) * NN + c0 + lc];
        ushort4 hi, lo;
        hi.x = f2bf(v.x); lo.x = f2bf(v.x - bf2f(hi.x));
        hi.y = f2bf(v.y); lo.y = f2bf(v.y - bf2f(hi.y));
        hi.z = f2bf(v.z); lo.z = f2bf(v.z - bf2f(hi.z));
        hi.w = f2bf(v.w); lo.w = f2bf(v.w - bf2f(hi.w));
        *(ushort4*)&xhi[(r0 + lr) * NN + c0 + lc] = hi;
        *(ushort4*)&xlo[(r0 + lr) * NN + c0 + lc] = lo;
        if (blockIdx.x == 0 && t < 32) out[r0 + t] = b3[0];
        return;
    }
    const float* src = (z == 1) ? W2 : W1;
    float4 v = *(const float4*)&src[(r0 + lr) * NN + c0 + lc];
    if (z == 1) {
        ushort4 h;
        h.x = f2bf(v.x); h.y = f2bf(v.y); h.z = f2bf(v.z); h.w = f2bf(v.w);
        *(ushort4*)&W2b[(r0 + lr) * NN + c0 + lc] = h;
    }
    T[lr][lc + 0] = v.x; T[lr][lc + 1] = v.y;
    T[lr][lc + 2] = v.z; T[lr][lc + 3] = v.w;
    __syncthreads();
    unsigned short* dh = (z == 1) ? W2th : W1th;
    unsigned short* dl = (z == 1) ? W2tl : W1tl;
    float a0 = T[lc + 0][lr], a1 = T[lc + 1][lr];
    float a2 = T[lc + 2][lr], a3 = T[lc + 3][lr];
    ushort4 hi, lo;
    hi.x = f2bf(a0); lo.x = f2bf(a0 - bf2f(hi.x));
    hi.y = f2bf(a1); lo.y = f2bf(a1 - bf2f(hi.y));
    hi.z = f2bf(a2); lo.z = f2bf(a2 - bf2f(hi.z));
    hi.w = f2bf(a3); lo.w = f2bf(a3 - bf2f(hi.w));
    *(ushort4*)&dh[(c0 + lr) * NN + r0 + lc] = hi;
    *(ushort4*)&dl[(c0 + lr) * NN + r0 + lc] = lo;
}

// ---- fwd: z = A@B + bias via split-bf16 MFMA, K-split-4 ------------------
// fwd1 epilogue: h=relu(z) -> Chi/Clo.   fwd2: H2b/G2b + out GEMV.

__global__ __launch_bounds__(256, 4) void fwd1(
    const unsigned short* __restrict__ Ahi, const unsigned short* __restrict__ Alo,
    const unsigned short* __restrict__ Bhi, const unsigned short* __restrict__ Blo,
    const float* __restrict__ bias,
    unsigned short* __restrict__ Chi, unsigned short* __restrict__ Clo) {
    __shared__ v4f red[3][64];
    const int t = threadIdx.x, wave = t >> 6, lane = t & 63;
    const int r = lane & 15, quad = lane >> 4;
    const int i0 = (blockIdx.x >> 5) * 16, j0 = (blockIdx.x & 31) * 16;
    const int kw = wave * 128;
    const int ao = (i0 + r) * NN + kw + quad * 8;
    const int bo = (j0 + r) * NN + kw + quad * 8;
    v4f hh = {0.f, 0.f, 0.f, 0.f}, lh = hh, hl = hh;
    #pragma unroll
    for (int k0 = 0; k0 < 128; k0 += 32) {
        v8s ah = *(const v8s*)(Ahi + ao + k0);
        v8s al = *(const v8s*)(Alo + ao + k0);
        v8s bh = *(const v8s*)(Bhi + bo + k0);
        v8s bl = *(const v8s*)(Blo + bo + k0);
        hh = __builtin_amdgcn_mfma_f32_16x16x32_bf16(ah, bh, hh, 0, 0, 0);
        lh = __builtin_amdgcn_mfma_f32_16x16x32_bf16(al, bh, lh, 0, 0, 0);
        hl = __builtin_amdgcn_mfma_f32_16x16x32_bf16(ah, bl, hl, 0, 0, 0);
    }
    v4f z = (hh + lh) + hl;
    if (wave) red[wave - 1][lane] = z;
    __syncthreads();
    if (wave == 0) {
        z += red[0][lane]; z += red[1][lane]; z += red[2][lane];
        const float bj = bias[j0 + r];
        #pragma unroll
        for (int rr = 0; rr < 4; ++rr) {
            const int i = i0 + quad * 4 + rr, j = j0 + r;
            float zv = z[rr] + bj;
            float h = zv > 0.f ? zv : 0.f;
            unsigned short hi = f2bf(h);
            Chi[i * NN + j] = hi;
            Clo[i * NN + j] = f2bf(h - bf2f(hi));
        }
    }
}

__global__ __launch_bounds__(256, 4) void fwd2(
    const unsigned short* __restrict__ Ahi, const unsigned short* __restrict__ Alo,
    const unsigned short* __restrict__ Bhi, const unsigned short* __restrict__ Blo,
    const float* __restrict__ b2, const float* __restrict__ w3,
    unsigned short* __restrict__ H2b, unsigned short* __restrict__ G2b,
    float* __restrict__ out) {
    __shared__ v4f red[3][64];
    const int t = threadIdx.x, wave = t >> 6, lane = t & 63;
    const int r = lane & 15, quad = lane >> 4;
    const int i0 = (blockIdx.x >> 5) * 16, j0 = (blockIdx.x & 31) * 16;
    const int kw = wave * 128;
    const int ao = (i0 + r) * NN + kw + quad * 8;
    const int bo = (j0 + r) * NN + kw + quad * 8;
    v4f hh = {0.f, 0.f, 0.f, 0.f}, lh = hh, hl = hh;
    #pragma unroll
    for (int k0 = 0; k0 < 128; k0 += 32) {
        v8s ah = *(const v8s*)(Ahi + ao + k0);
        v8s al = *(const v8s*)(Alo + ao + k0);
        v8s bh = *(const v8s*)(Bhi + bo + k0);
        v8s bl = *(const v8s*)(Blo + bo + k0);
        hh = __builtin_amdgcn_mfma_f32_16x16x32_bf16(ah, bh, hh, 0, 0, 0);
        lh = __builtin_amdgcn_mfma_f32_16x16x32_bf16(al, bh, lh, 0, 0, 0);
        hl = __builtin_amdgcn_mfma_f32_16x16x32_bf16(ah, bl, hl, 0, 0, 0);
    }
    v4f z = (hh + lh) + hl;
    if (wave) red[wave - 1][lane] = z;
    __syncthreads();
    if (wave == 0) {
        z += red[0][lane]; z += red[1][lane]; z += red[2][lane];
        const float bj = b2[j0 + r];
        const float wj = w3[j0 + r];
        const unsigned short wjb = f2bf(wj);
        #pragma unroll
        for (int rr = 0; rr < 4; ++rr) {
            const int i = i0 + quad * 4 + rr, j = j0 + r;
            float zv = z[rr] + bj;
            float h = zv > 0.f ? zv : 0.f;
            H2b[i * NN + j] = f2bf(h);
            G2b[i * NN + j] = (zv > 0.f) ? wjb : (unsigned short)0;
            float p = h * wj;
            p += __shfl_xor(p, 1, 64);
            p += __shfl_xor(p, 2, 64);
            p += __shfl_xor(p, 4, 64);
            p += __shfl_xor(p, 8, 64);
            if (r == 0) atomicAdd(&out[i], p);
        }
    }
}

// ---- g1: G1b = 1{H1>0} ⊙ (G2b @ W2^T), K-split-4 -------------------------
__global__ __launch_bounds__(256, 4) void g1k(
    const unsigned short* __restrict__ G2b, const unsigned short* __restrict__ W2b,
    const unsigned short* __restrict__ H1b, unsigned short* __restrict__ G1b) {
    __shared__ v4f red[3][64];
    const int t = threadIdx.x, wave = t >> 6, lane = t & 63;
    const int r = lane & 15, quad = lane >> 4;
    const int i0 = (blockIdx.x >> 5) * 16, c0 = (blockIdx.x & 31) * 16;
    const int kw = wave * 128;
    const unsigned short* arow = G2b + (i0 + r) * NN + kw + quad * 8;
    const unsigned short* brow = W2b + (c0 + r) * NN + kw + quad * 8;
    v4f acc = {0.f, 0.f, 0.f, 0.f};
    #pragma unroll
    for (int k0 = 0; k0 < 128; k0 += 32) {
        v8s a = *(const v8s*)(arow + k0);
        v8s b = *(const v8s*)(brow + k0);
        acc = __builtin_amdgcn_mfma_f32_16x16x32_bf16(a, b, acc, 0, 0, 0);
    }
    if (wave) red[wave - 1][lane] = acc;
    __syncthreads();
    if (wave == 0) {
        acc += red[0][lane]; acc += red[1][lane]; acc += red[2][lane];
        #pragma unroll
        for (int rr = 0; rr < 4; ++rr) {
            const int i = i0 + quad * 4 + rr;
            const int c = c0 + r;
            float v = (H1b[i * NN + c] != 0) ? acc[rr] : 0.f;
            G1b[i * NN + c] = f2bf(v);
        }
    }
}

// ---- gram: 5 fused bf16 syrks, K-split-4 ---------------------------------
__global__ __launch_bounds__(256, 4) void gramk(
    const unsigned short* __restrict__ Xb, const unsigned short* __restrict__ H1b,
    const unsigned short* __restrict__ G1b, const unsigned short* __restrict__ H2b,
    const unsigned short* __restrict__ G2b, float* __restrict__ gram) {
    __shared__ v4f red[3][5][64];
    const int t = threadIdx.x, wave = t >> 6, lane = t & 63;
    const int r = lane & 15, quad = lane >> 4;
    const int i0 = (blockIdx.x >> 5) * 16, j0 = (blockIdx.x & 31) * 16;
    const int kw = wave * 128;
    const int ao = (i0 + r) * NN + kw + quad * 8;
    const int bo = (j0 + r) * NN + kw + quad * 8;
    v4f a0 = {0.f,0.f,0.f,0.f}, a1 = a0, a2 = a0, a3 = a0, a4 = a0;
    #pragma unroll
    for (int k0 = 0; k0 < 128; k0 += 32) {
        v8s xa = *(const v8s*)(Xb  + ao + k0), xb2 = *(const v8s*)(Xb  + bo + k0);
        v8s ha = *(const v8s*)(H1b + ao + k0), hb  = *(const v8s*)(H1b + bo + k0);
        v8s ga = *(const v8s*)(G1b + ao + k0), gb  = *(const v8s*)(G1b + bo + k0);
        v8s ua = *(const v8s*)(H2b + ao + k0), ub  = *(const v8s*)(H2b + bo + k0);
        v8s va = *(const v8s*)(G2b + ao + k0), vb  = *(const v8s*)(G2b + bo + k0);
        a0 = __builtin_amdgcn_mfma_f32_16x16x32_bf16(xa, xb2, a0, 0, 0, 0);
        a1 = __builtin_amdgcn_mfma_f32_16x16x32_bf16(ha, hb,  a1, 0, 0, 0);
        a2 = __builtin_amdgcn_mfma_f32_16x16x32_bf16(ga, gb,  a2, 0, 0, 0);
        a3 = __builtin_amdgcn_mfma_f32_16x16x32_bf16(ua, ub,  a3, 0, 0, 0);
        a4 = __builtin_amdgcn_mfma_f32_16x16x32_bf16(va, vb,  a4, 0, 0, 0);
    }
    if (wave) {
        red[wave - 1][0][lane] = a0; red[wave - 1][1][lane] = a1;
        red[wave - 1][2][lane] = a2; red[wave - 1][3][lane] = a3;
        red[wave - 1][4][lane] = a4;
    }
    __syncthreads();
    if (wave == 0) {
        #pragma unroll
        for (int w = 0; w < 3; ++w) {
            a0 += red[w][0][lane]; a1 += red[w][1][lane];
            a2 += red[w][2][lane]; a3 += red[w][3][lane];
            a4 += red[w][4][lane];
        }
        #pragma unroll
        for (int rr = 0; rr < 4; ++rr) {
            const int i = i0 + quad * 4 + rr;
            const int j = j0 + r;
            float g = 1.f + a3[rr] + a4[rr] * (1.f + a1[rr]) + a2[rr] * (1.f + a0[rr]);
            gram[i * NN + j] = g;
        }
    }
}

extern "C" void kernel_launch(void* const* d_in, const int* in_sizes, int n_in,
                              void* d_out, int out_size, void* d_ws, size_t ws_size,
                              hipStream_t stream) {
    const float* x  = (const float*)d_in[0];
    const float* W1 = (const float*)d_in[1];
    const float* b1 = (const float*)d_in[2];
    const float* W2 = (const float*)d_in[3];
    const float* b2 = (const float*)d_in[4];
    const float* w3 = (const float*)d_in[5];
    const float* b3 = (const float*)d_in[6];

    float* out  = (float*)d_out;
    float* gram = out + NN;

    unsigned short* p    = (unsigned short*)d_ws;
    unsigned short* xhi  = p;  p += NN * NN;
    unsigned short* xlo  = p;  p += NN * NN;
    unsigned short* W1th = p;  p += NN * NN;
    unsigned short* W1tl = p;  p += NN * NN;
    unsigned short* W2th = p;  p += NN * NN;
    unsigned short* W2tl = p;  p += NN * NN;
    unsigned short* W2b  = p;  p += NN * NN;
    unsigned short* H1b  = p;  p += NN * NN;
    unsigned short* H1lo = p;  p += NN * NN;
    unsigned short* H2b  = p;  p += NN * NN;
    unsigned short* G2b  = p;  p += NN * NN;
    unsigned short* G1b  = p;  p += NN * NN;

    dim3 blk(256);
    prep <<<dim3(16, 16, 3), blk, 0, stream>>>(x, W1, W2, b3, xhi, xlo,
                                               W1th, W1tl, W2th, W2tl, W2b, out);
    fwd1 <<<dim3(1024), blk, 0, stream>>>(xhi, xlo, W1th, W1tl, b1, H1b, H1lo);
    fwd2 <<<dim3(1024), blk, 0, stream>>>(H1b, H1lo, W2th, W2tl, b2, w3,
                                          H2b, G2b, out);
    g1k  <<<dim3(1024), blk, 0, stream>>>(G2b, W2b, H1b, G1b);
    gramk<<<dim3(1024), blk, 0, stream>>>(xhi, H1b, G1b, H2b, G2b, gram);
}

// Round 7
// 117.315 us; speedup vs baseline: 2.0301x; 1.0072x over previous
//
#include <hip/hip_runtime.h>

// B=D=H=512. Inputs fp32: x, W1, b1, W2, b2, w3, b3.
// d_out = out[512] ++ gram[512,512] (fp32).
// G = 1 + H2H2^T + (1+H1H1^T)⊙(G2G2^T) + (1+XX^T)⊙(G1G1^T)
//   g2 = w3⊙1{z2>0};  g1 = (W2 g2)⊙1{z1>0}
// 4 kernels (prep folded away):
//   fwd1: stages W1^T hi/lo via LDS from fp32; x split in-register; j0==0
//         blocks dump xhi (for gramk) and init out=b3.  -> H1b, H1lo
//   fwd2: stages W2^T hi/lo via LDS; i0==0 blocks dump plain-bf16 W2 rows
//         (g1k's B operand).  -> H2b, G2b, out += h2·w3
//   g1k : G1 = 1{H1>0} ⊙ (G2 @ W2^T)   (bf16 MFMA, no LDS)
//   gramk: 5 fused bf16 syrks -> gram
// All tiles 32x32/block (4 waves = quadrants, full K) — measured-best shape.

#define NN 512

typedef __attribute__((ext_vector_type(8))) short v8s;
typedef __attribute__((ext_vector_type(4))) float v4f;

static __device__ __forceinline__ unsigned short f2bf(float f) {
    union { float f; unsigned u; } v; v.f = f;
    unsigned r = v.u + 0x7FFF + ((v.u >> 16) & 1);
    return (unsigned short)(r >> 16);
}
static __device__ __forceinline__ float bf2f(unsigned short h) {
    union { unsigned u; float f; } v; v.u = ((unsigned)h) << 16;
    return v.f;
}

// ---- fwd1: h1 = relu(x@W1 + b1), split-bf16; dumps xhi; inits out --------
__global__ __launch_bounds__(256) void fwd1(
    const float* __restrict__ x, const float* __restrict__ W1,
    const float* __restrict__ b1, const float* __restrict__ b3,
    unsigned short* __restrict__ xhi_out,
    unsigned short* __restrict__ H1b, unsigned short* __restrict__ H1lo,
    float* __restrict__ out) {
    __shared__ unsigned short Bh[32][520];  // W1^T hi: [col][k], pad->520
    __shared__ unsigned short Bl[32][520];  // W1^T lo
    const int t = threadIdx.x;
    const int bx = blockIdx.x & 15, by = blockIdx.x >> 4;
    const int i0b = by * 32, j0b = bx * 32;

    // stage W1[:, j0b..j0b+31] -> LDS transposed, split hi/lo
    {
        const int c4 = (t & 7) * 4;
        const int rb = t >> 3;  // 0..31
        #pragma unroll
        for (int rnd = 0; rnd < 16; ++rnd) {
            const int row = rnd * 32 + rb;
            float4 v = *(const float4*)&W1[row * NN + j0b + c4];
            unsigned short h;
            h = f2bf(v.x); Bh[c4 + 0][row] = h; Bl[c4 + 0][row] = f2bf(v.x - bf2f(h));
            h = f2bf(v.y); Bh[c4 + 1][row] = h; Bl[c4 + 1][row] = f2bf(v.y - bf2f(h));
            h = f2bf(v.z); Bh[c4 + 2][row] = h; Bl[c4 + 2][row] = f2bf(v.z - bf2f(h));
            h = f2bf(v.w); Bh[c4 + 3][row] = h; Bl[c4 + 3][row] = f2bf(v.w - bf2f(h));
        }
    }
    if (j0b == 0 && t < 32) out[i0b + t] = b3[0];
    __syncthreads();

    const int wave = t >> 6, lane = t & 63;
    const int r = lane & 15, quad = lane >> 4;
    const int i0 = i0b + 16 * (wave >> 1);
    const int j0 = j0b + 16 * (wave & 1);
    const int jl = 16 * (wave & 1) + r;          // LDS col index
    const float* xrow = x + (i0 + r) * NN;
    const bool dumpx = (j0b == 0) && ((wave & 1) == 0);

    v4f hh = {0.f, 0.f, 0.f, 0.f}, lh = hh, hl = hh;
    #pragma unroll
    for (int k0 = 0; k0 < NN; k0 += 32) {
        const int k = k0 + quad * 8;
        float4 xa = *(const float4*)&xrow[k];
        float4 xb = *(const float4*)&xrow[k + 4];
        v8s ah, al;
        {
            float vv[8] = {xa.x, xa.y, xa.z, xa.w, xb.x, xb.y, xb.z, xb.w};
            #pragma unroll
            for (int e = 0; e < 8; ++e) {
                unsigned short h = f2bf(vv[e]);
                ((unsigned short*)&ah)[e] = h;
                ((unsigned short*)&al)[e] = f2bf(vv[e] - bf2f(h));
            }
        }
        v8s bh = *(const v8s*)&Bh[jl][k];
        v8s bl = *(const v8s*)&Bl[jl][k];
        hh = __builtin_amdgcn_mfma_f32_16x16x32_bf16(ah, bh, hh, 0, 0, 0);
        lh = __builtin_amdgcn_mfma_f32_16x16x32_bf16(al, bh, lh, 0, 0, 0);
        hl = __builtin_amdgcn_mfma_f32_16x16x32_bf16(ah, bl, hl, 0, 0, 0);
        if (dumpx) *(v8s*)&xhi_out[(i0 + r) * NN + k] = ah;
    }
    const float bj = b1[j0 + r];
    #pragma unroll
    for (int rr = 0; rr < 4; ++rr) {
        const int i = i0 + quad * 4 + rr, j = j0 + r;
        float zv = (hh[rr] + lh[rr]) + hl[rr] + bj;
        float h = zv > 0.f ? zv : 0.f;
        unsigned short hi = f2bf(h);
        H1b[i * NN + j]  = hi;
        H1lo[i * NN + j] = f2bf(h - bf2f(hi));
    }
}

// ---- fwd2: z2 = H1@W2 + b2; dumps W2b rows; H2b/G2b/out ------------------
__global__ __launch_bounds__(256) void fwd2(
    const unsigned short* __restrict__ Ahi, const unsigned short* __restrict__ Alo,
    const float* __restrict__ W2, const float* __restrict__ b2,
    const float* __restrict__ w3, unsigned short* __restrict__ W2b,
    unsigned short* __restrict__ H2b, unsigned short* __restrict__ G2b,
    float* __restrict__ out) {
    __shared__ unsigned short Bh[32][520];
    __shared__ unsigned short Bl[32][520];
    const int t = threadIdx.x;
    const int bx = blockIdx.x & 15, by = blockIdx.x >> 4;
    const int i0b = by * 32, j0b = bx * 32;

    {
        const int c4 = (t & 7) * 4;
        const int rb = t >> 3;
        const bool dumpw = (i0b == 0);
        #pragma unroll
        for (int rnd = 0; rnd < 16; ++rnd) {
            const int row = rnd * 32 + rb;
            float4 v = *(const float4*)&W2[row * NN + j0b + c4];
            ushort4 h4;
            h4.x = f2bf(v.x); h4.y = f2bf(v.y); h4.z = f2bf(v.z); h4.w = f2bf(v.w);
            Bh[c4 + 0][row] = h4.x; Bl[c4 + 0][row] = f2bf(v.x - bf2f(h4.x));
            Bh[c4 + 1][row] = h4.y; Bl[c4 + 1][row] = f2bf(v.y - bf2f(h4.y));
            Bh[c4 + 2][row] = h4.z; Bl[c4 + 2][row] = f2bf(v.z - bf2f(h4.z));
            Bh[c4 + 3][row] = h4.w; Bl[c4 + 3][row] = f2bf(v.w - bf2f(h4.w));
            if (dumpw) *(ushort4*)&W2b[row * NN + j0b + c4] = h4;
        }
    }
    __syncthreads();

    const int wave = t >> 6, lane = t & 63;
    const int r = lane & 15, quad = lane >> 4;
    const int i0 = i0b + 16 * (wave >> 1);
    const int j0 = j0b + 16 * (wave & 1);
    const int jl = 16 * (wave & 1) + r;
    const int ao = (i0 + r) * NN + quad * 8;

    v4f hh = {0.f, 0.f, 0.f, 0.f}, lh = hh, hl = hh;
    #pragma unroll
    for (int k0 = 0; k0 < NN; k0 += 32) {
        const int k = k0 + quad * 8;
        v8s ah = *(const v8s*)(Ahi + ao + k0);
        v8s al = *(const v8s*)(Alo + ao + k0);
        v8s bh = *(const v8s*)&Bh[jl][k];
        v8s bl = *(const v8s*)&Bl[jl][k];
        hh = __builtin_amdgcn_mfma_f32_16x16x32_bf16(ah, bh, hh, 0, 0, 0);
        lh = __builtin_amdgcn_mfma_f32_16x16x32_bf16(al, bh, lh, 0, 0, 0);
        hl = __builtin_amdgcn_mfma_f32_16x16x32_bf16(ah, bl, hl, 0, 0, 0);
    }
    const float bj = b2[j0 + r];
    const float wj = w3[j0 + r];
    const unsigned short wjb = f2bf(wj);
    #pragma unroll
    for (int rr = 0; rr < 4; ++rr) {
        const int i = i0 + quad * 4 + rr, j = j0 + r;
        float zv = (hh[rr] + lh[rr]) + hl[rr] + bj;
        float h = zv > 0.f ? zv : 0.f;
        H2b[i * NN + j] = f2bf(h);
        G2b[i * NN + j] = (zv > 0.f) ? wjb : (unsigned short)0;
        float p = h * wj;
        p += __shfl_xor(p, 1, 64);
        p += __shfl_xor(p, 2, 64);
        p += __shfl_xor(p, 4, 64);
        p += __shfl_xor(p, 8, 64);
        if (r == 0) atomicAdd(&out[i], p);
    }
}

// ---- g1: G1b = 1{H1>0} ⊙ (G2b @ W2^T), bf16 MFMA, no LDS -----------------
__global__ __launch_bounds__(256) void g1k(
    const unsigned short* __restrict__ G2b, const unsigned short* __restrict__ W2b,
    const unsigned short* __restrict__ H1b, unsigned short* __restrict__ G1b) {
    const int t = threadIdx.x;
    const int wave = t >> 6, lane = t & 63;
    const int r = lane & 15, quad = lane >> 4;
    const int i0 = blockIdx.y * 32 + 16 * (wave >> 1);
    const int c0 = blockIdx.x * 32 + 16 * (wave & 1);
    const unsigned short* arow = G2b + (i0 + r) * NN + quad * 8;
    const unsigned short* brow = W2b + (c0 + r) * NN + quad * 8;
    v4f acc = {0.f, 0.f, 0.f, 0.f};
    #pragma unroll
    for (int k0 = 0; k0 < NN; k0 += 32) {
        v8s a = *(const v8s*)(arow + k0);
        v8s b = *(const v8s*)(brow + k0);
        acc = __builtin_amdgcn_mfma_f32_16x16x32_bf16(a, b, acc, 0, 0, 0);
    }
    #pragma unroll
    for (int rr = 0; rr < 4; ++rr) {
        const int i = i0 + quad * 4 + rr;
        const int c = c0 + r;
        float v = (H1b[i * NN + c] != 0) ? acc[rr] : 0.f;
        G1b[i * NN + c] = f2bf(v);
    }
}

// ---- gram: 5 fused bf16 syrks, no LDS ------------------------------------
__global__ __launch_bounds__(256) void gramk(
    const unsigned short* __restrict__ Xb, const unsigned short* __restrict__ H1b,
    const unsigned short* __restrict__ G1b, const unsigned short* __restrict__ H2b,
    const unsigned short* __restrict__ G2b, float* __restrict__ gram) {
    const int t = threadIdx.x;
    const int wave = t >> 6, lane = t & 63;
    const int r = lane & 15, quad = lane >> 4;
    const int i0 = blockIdx.y * 32 + 16 * (wave >> 1);
    const int j0 = blockIdx.x * 32 + 16 * (wave & 1);
    const int ao = (i0 + r) * NN + quad * 8;
    const int bo = (j0 + r) * NN + quad * 8;
    v4f a0 = {0.f,0.f,0.f,0.f}, a1 = a0, a2 = a0, a3 = a0, a4 = a0;
    #pragma unroll
    for (int k0 = 0; k0 < NN; k0 += 32) {
        v8s xa = *(const v8s*)(Xb  + ao + k0), xb2 = *(const v8s*)(Xb  + bo + k0);
        v8s ha = *(const v8s*)(H1b + ao + k0), hb  = *(const v8s*)(H1b + bo + k0);
        v8s ga = *(const v8s*)(G1b + ao + k0), gb  = *(const v8s*)(G1b + bo + k0);
        v8s ua = *(const v8s*)(H2b + ao + k0), ub  = *(const v8s*)(H2b + bo + k0);
        v8s va = *(const v8s*)(G2b + ao + k0), vb  = *(const v8s*)(G2b + bo + k0);
        a0 = __builtin_amdgcn_mfma_f32_16x16x32_bf16(xa, xb2, a0, 0, 0, 0);
        a1 = __builtin_amdgcn_mfma_f32_16x16x32_bf16(ha, hb,  a1, 0, 0, 0);
        a2 = __builtin_amdgcn_mfma_f32_16x16x32_bf16(ga, gb,  a2, 0, 0, 0);
        a3 = __builtin_amdgcn_mfma_f32_16x16x32_bf16(ua, ub,  a3, 0, 0, 0);
        a4 = __builtin_amdgcn_mfma_f32_16x16x32_bf16(va, vb,  a4, 0, 0, 0);
    }
    #pragma unroll
    for (int rr = 0; rr < 4; ++rr) {
        const int i = i0 + quad * 4 + rr;
        const int j = j0 + r;
        float g = 1.f + a3[rr] + a4[rr] * (1.f + a1[rr]) + a2[rr] * (1.f + a0[rr]);
        gram[i * NN + j] = g;
    }
}

extern "C" void kernel_launch(void* const* d_in, const int* in_sizes, int n_in,
                              void* d_out, int out_size, void* d_ws, size_t ws_size,
                              hipStream_t stream) {
    const float* x  = (const float*)d_in[0];
    const float* W1 = (const float*)d_in[1];
    const float* b1 = (const float*)d_in[2];
    const float* W2 = (const float*)d_in[3];
    const float* b2 = (const float*)d_in[4];
    const float* w3 = (const float*)d_in[5];
    const float* b3 = (const float*)d_in[6];

    float* out  = (float*)d_out;
    float* gram = out + NN;

    // 7 bf16 [512][512] arrays, 512 KB each
    unsigned short* p    = (unsigned short*)d_ws;
    unsigned short* xhi  = p;  p += NN * NN;
    unsigned short* H1b  = p;  p += NN * NN;
    unsigned short* H1lo = p;  p += NN * NN;
    unsigned short* H2b  = p;  p += NN * NN;
    unsigned short* G2b  = p;  p += NN * NN;
    unsigned short* G1b  = p;  p += NN * NN;
    unsigned short* W2b  = p;  p += NN * NN;

    dim3 blk(256);
    fwd1 <<<dim3(256), blk, 0, stream>>>(x, W1, b1, b3, xhi, H1b, H1lo, out);
    fwd2 <<<dim3(256), blk, 0, stream>>>(H1b, H1lo, W2, b2, w3, W2b,
                                         H2b, G2b, out);
    g1k  <<<dim3(16, 16), blk, 0, stream>>>(G2b, W2b, H1b, G1b);
    gramk<<<dim3(16, 16), blk, 0, stream>>>(xhi, H1b, G1b, H2b, G2b, gram);
}

// Round 8
// 116.688 us; speedup vs baseline: 2.0410x; 1.0054x over previous
//
#include <hip/hip_runtime.h>

// B=D=H=512. Inputs fp32: x, W1, b1, W2, b2, w3, b3.
// d_out = out[512] ++ gram[512,512] (fp32).
// G = 1 + H2H2^T + (1+H1H1^T)⊙(G2G2^T) + (1+XX^T)⊙(G1G1^T)
//   g2 = w3⊙1{z2>0};  g1 = (W2 g2)⊙1{z1>0}
// R4 structure (measured best: 114.7us): 5 dispatches, 32x32 tile/block,
// no LDS in MFMA K-loops. R8 delta: fwd1 splits x in-register from fp32
// (xlo stream removed; prep z=2 writes xhi only).

#define NN 512

typedef __attribute__((ext_vector_type(8))) short v8s;
typedef __attribute__((ext_vector_type(4))) float v4f;

static __device__ __forceinline__ unsigned short f2bf(float f) {
    union { float f; unsigned u; } v; v.f = f;
    unsigned r = v.u + 0x7FFF + ((v.u >> 16) & 1);
    return (unsigned short)(r >> 16);
}
static __device__ __forceinline__ float bf2f(unsigned short h) {
    union { unsigned u; float f; } v; v.u = ((unsigned)h) << 16;
    return v.f;
}

// ---- prep: z=0: W1 transpose+split; z=1: W2 transpose+split + plain W2b;
//            z=2: xhi + out[i]=b3 ------------------------------------------
__global__ __launch_bounds__(256) void prep(
    const float* __restrict__ x, const float* __restrict__ W1,
    const float* __restrict__ W2, const float* __restrict__ b3,
    unsigned short* __restrict__ xhi,
    unsigned short* __restrict__ W1th, unsigned short* __restrict__ W1tl,
    unsigned short* __restrict__ W2th, unsigned short* __restrict__ W2tl,
    unsigned short* __restrict__ W2b, float* __restrict__ out) {
    __shared__ float T[32][33];
    const int t = threadIdx.x;
    const int lr = t >> 3, lc = (t & 7) * 4;
    const int r0 = blockIdx.y * 32, c0 = blockIdx.x * 32;
    const int z = blockIdx.z;
    if (z == 2) {
        float4 v = *(const float4*)&x[(r0 + lr) * NN + c0 + lc];
        ushort4 hi;
        hi.x = f2bf(v.x); hi.y = f2bf(v.y); hi.z = f2bf(v.z); hi.w = f2bf(v.w);
        *(ushort4*)&xhi[(r0 + lr) * NN + c0 + lc] = hi;
        if (blockIdx.x == 0 && t < 32) out[r0 + t] = b3[0];
        return;
    }
    const float* src = (z == 1) ? W2 : W1;
    float4 v = *(const float4*)&src[(r0 + lr) * NN + c0 + lc];
    if (z == 1) {
        ushort4 h;
        h.x = f2bf(v.x); h.y = f2bf(v.y); h.z = f2bf(v.z); h.w = f2bf(v.w);
        *(ushort4*)&W2b[(r0 + lr) * NN + c0 + lc] = h;
    }
    T[lr][lc + 0] = v.x; T[lr][lc + 1] = v.y;
    T[lr][lc + 2] = v.z; T[lr][lc + 3] = v.w;
    __syncthreads();
    unsigned short* dh = (z == 1) ? W2th : W1th;
    unsigned short* dl = (z == 1) ? W2tl : W1tl;
    float a0 = T[lc + 0][lr], a1 = T[lc + 1][lr];
    float a2 = T[lc + 2][lr], a3 = T[lc + 3][lr];
    ushort4 hi, lo;
    hi.x = f2bf(a0); lo.x = f2bf(a0 - bf2f(hi.x));
    hi.y = f2bf(a1); lo.y = f2bf(a1 - bf2f(hi.y));
    hi.z = f2bf(a2); lo.z = f2bf(a2 - bf2f(hi.z));
    hi.w = f2bf(a3); lo.w = f2bf(a3 - bf2f(hi.w));
    *(ushort4*)&dh[(c0 + lr) * NN + r0 + lc] = hi;
    *(ushort4*)&dl[(c0 + lr) * NN + r0 + lc] = lo;
}

// ---- fwd1: h = relu(x@W1+b1) via split-bf16 MFMA; x split in-register ----
__global__ __launch_bounds__(256) void fwd1(
    const float* __restrict__ x,
    const unsigned short* __restrict__ Bhi, const unsigned short* __restrict__ Blo,
    const float* __restrict__ bias,
    unsigned short* __restrict__ Chi, unsigned short* __restrict__ Clo) {
    const int t = threadIdx.x;
    const int wave = t >> 6, lane = t & 63;
    const int r = lane & 15, quad = lane >> 4;
    const int i0 = blockIdx.y * 32 + 16 * (wave >> 1);
    const int j0 = blockIdx.x * 32 + 16 * (wave & 1);
    const float* xrow = x + (i0 + r) * NN + quad * 8;
    const int bo = (j0 + r) * NN + quad * 8;
    v4f hh = {0.f, 0.f, 0.f, 0.f}, lh = hh, hl = hh;
    #pragma unroll
    for (int k0 = 0; k0 < NN; k0 += 32) {
        float4 xa = *(const float4*)(xrow + k0);
        float4 xb = *(const float4*)(xrow + k0 + 4);
        v8s ah, al;
        {
            float vv[8] = {xa.x, xa.y, xa.z, xa.w, xb.x, xb.y, xb.z, xb.w};
            #pragma unroll
            for (int e = 0; e < 8; ++e) {
                unsigned short h = f2bf(vv[e]);
                ((unsigned short*)&ah)[e] = h;
                ((unsigned short*)&al)[e] = f2bf(vv[e] - bf2f(h));
            }
        }
        v8s bh = *(const v8s*)(Bhi + bo + k0);
        v8s bl = *(const v8s*)(Blo + bo + k0);
        hh = __builtin_amdgcn_mfma_f32_16x16x32_bf16(ah, bh, hh, 0, 0, 0);
        lh = __builtin_amdgcn_mfma_f32_16x16x32_bf16(al, bh, lh, 0, 0, 0);
        hl = __builtin_amdgcn_mfma_f32_16x16x32_bf16(ah, bl, hl, 0, 0, 0);
    }
    const float bj = bias[j0 + r];
    #pragma unroll
    for (int rr = 0; rr < 4; ++rr) {
        const int i = i0 + quad * 4 + rr, j = j0 + r;
        float zv = (hh[rr] + lh[rr]) + hl[rr] + bj;
        float h = zv > 0.f ? zv : 0.f;
        unsigned short hi = f2bf(h);
        Chi[i * NN + j] = hi;
        Clo[i * NN + j] = f2bf(h - bf2f(hi));
    }
}

// ---- fwd2: z2 = H1@W2+b2; writes H2b, G2b, out += h2·w3 ------------------
__global__ __launch_bounds__(256) void fwd2(
    const unsigned short* __restrict__ Ahi, const unsigned short* __restrict__ Alo,
    const unsigned short* __restrict__ Bhi, const unsigned short* __restrict__ Blo,
    const float* __restrict__ b2, const float* __restrict__ w3,
    unsigned short* __restrict__ H2b, unsigned short* __restrict__ G2b,
    float* __restrict__ out) {
    const int t = threadIdx.x;
    const int wave = t >> 6, lane = t & 63;
    const int r = lane & 15, quad = lane >> 4;
    const int i0 = blockIdx.y * 32 + 16 * (wave >> 1);
    const int j0 = blockIdx.x * 32 + 16 * (wave & 1);
    const int ao = (i0 + r) * NN + quad * 8;
    const int bo = (j0 + r) * NN + quad * 8;
    v4f hh = {0.f, 0.f, 0.f, 0.f}, lh = hh, hl = hh;
    #pragma unroll
    for (int k0 = 0; k0 < NN; k0 += 32) {
        v8s ah = *(const v8s*)(Ahi + ao + k0);
        v8s al = *(const v8s*)(Alo + ao + k0);
        v8s bh = *(const v8s*)(Bhi + bo + k0);
        v8s bl = *(const v8s*)(Blo + bo + k0);
        hh = __builtin_amdgcn_mfma_f32_16x16x32_bf16(ah, bh, hh, 0, 0, 0);
        lh = __builtin_amdgcn_mfma_f32_16x16x32_bf16(al, bh, lh, 0, 0, 0);
        hl = __builtin_amdgcn_mfma_f32_16x16x32_bf16(ah, bl, hl, 0, 0, 0);
    }
    const float bj = b2[j0 + r];
    const float wj = w3[j0 + r];
    const unsigned short wjb = f2bf(wj);
    #pragma unroll
    for (int rr = 0; rr < 4; ++rr) {
        const int i = i0 + quad * 4 + rr, j = j0 + r;
        float zv = (hh[rr] + lh[rr]) + hl[rr] + bj;
        float h = zv > 0.f ? zv : 0.f;
        H2b[i * NN + j] = f2bf(h);
        G2b[i * NN + j] = (zv > 0.f) ? wjb : (unsigned short)0;
        float p = h * wj;
        p += __shfl_xor(p, 1, 64);
        p += __shfl_xor(p, 2, 64);
        p += __shfl_xor(p, 4, 64);
        p += __shfl_xor(p, 8, 64);
        if (r == 0) atomicAdd(&out[i], p);
    }
}

// ---- g1: G1b[i,c] = 1{H1>0} * (G2b @ W2^T), bf16 MFMA --------------------
__global__ __launch_bounds__(256) void g1k(
    const unsigned short* __restrict__ G2b, const unsigned short* __restrict__ W2b,
    const unsigned short* __restrict__ H1b, unsigned short* __restrict__ G1b) {
    const int t = threadIdx.x;
    const int wave = t >> 6, lane = t & 63;
    const int r = lane & 15, quad = lane >> 4;
    const int i0 = blockIdx.y * 32 + 16 * (wave >> 1);
    const int c0 = blockIdx.x * 32 + 16 * (wave & 1);
    const unsigned short* arow = G2b + (i0 + r) * NN + quad * 8;
    const unsigned short* brow = W2b + (c0 + r) * NN + quad * 8;
    v4f acc = {0.f, 0.f, 0.f, 0.f};
    #pragma unroll
    for (int k0 = 0; k0 < NN; k0 += 32) {
        v8s a = *(const v8s*)(arow + k0);
        v8s b = *(const v8s*)(brow + k0);
        acc = __builtin_amdgcn_mfma_f32_16x16x32_bf16(a, b, acc, 0, 0, 0);
    }
    #pragma unroll
    for (int rr = 0; rr < 4; ++rr) {
        const int i = i0 + quad * 4 + rr;
        const int c = c0 + r;
        float v = (H1b[i * NN + c] != 0) ? acc[rr] : 0.f;
        G1b[i * NN + c] = f2bf(v);
    }
}

// ---- gram: 5 bf16 syrks fused, no LDS ------------------------------------
__global__ __launch_bounds__(256) void gramk(
    const unsigned short* __restrict__ Xb, const unsigned short* __restrict__ H1b,
    const unsigned short* __restrict__ G1b, const unsigned short* __restrict__ H2b,
    const unsigned short* __restrict__ G2b, float* __restrict__ gram) {
    const int t = threadIdx.x;
    const int wave = t >> 6, lane = t & 63;
    const int r = lane & 15, quad = lane >> 4;
    const int i0 = blockIdx.y * 32 + 16 * (wave >> 1);
    const int j0 = blockIdx.x * 32 + 16 * (wave & 1);
    const int ao = (i0 + r) * NN + quad * 8;
    const int bo = (j0 + r) * NN + quad * 8;
    v4f a0 = {0.f,0.f,0.f,0.f}, a1 = a0, a2 = a0, a3 = a0, a4 = a0;
    #pragma unroll
    for (int k0 = 0; k0 < NN; k0 += 32) {
        v8s xa = *(const v8s*)(Xb  + ao + k0), xb2 = *(const v8s*)(Xb  + bo + k0);
        v8s ha = *(const v8s*)(H1b + ao + k0), hb  = *(const v8s*)(H1b + bo + k0);
        v8s ga = *(const v8s*)(G1b + ao + k0), gb  = *(const v8s*)(G1b + bo + k0);
        v8s ua = *(const v8s*)(H2b + ao + k0), ub  = *(const v8s*)(H2b + bo + k0);
        v8s va = *(const v8s*)(G2b + ao + k0), vb  = *(const v8s*)(G2b + bo + k0);
        a0 = __builtin_amdgcn_mfma_f32_16x16x32_bf16(xa, xb2, a0, 0, 0, 0);
        a1 = __builtin_amdgcn_mfma_f32_16x16x32_bf16(ha, hb,  a1, 0, 0, 0);
        a2 = __builtin_amdgcn_mfma_f32_16x16x32_bf16(ga, gb,  a2, 0, 0, 0);
        a3 = __builtin_amdgcn_mfma_f32_16x16x32_bf16(ua, ub,  a3, 0, 0, 0);
        a4 = __builtin_amdgcn_mfma_f32_16x16x32_bf16(va, vb,  a4, 0, 0, 0);
    }
    #pragma unroll
    for (int rr = 0; rr < 4; ++rr) {
        const int i = i0 + quad * 4 + rr;
        const int j = j0 + r;
        float g = 1.f + a3[rr] + a4[rr] * (1.f + a1[rr]) + a2[rr] * (1.f + a0[rr]);
        gram[i * NN + j] = g;
    }
}

extern "C" void kernel_launch(void* const* d_in, const int* in_sizes, int n_in,
                              void* d_out, int out_size, void* d_ws, size_t ws_size,
                              hipStream_t stream) {
    const float* x  = (const float*)d_in[0];
    const float* W1 = (const float*)d_in[1];
    const float* b1 = (const float*)d_in[2];
    const float* W2 = (const float*)d_in[3];
    const float* b2 = (const float*)d_in[4];
    const float* w3 = (const float*)d_in[5];
    const float* b3 = (const float*)d_in[6];

    float* out  = (float*)d_out;
    float* gram = out + NN;

    // 11 bf16 [512][512] arrays, 512 KB each
    unsigned short* p    = (unsigned short*)d_ws;
    unsigned short* xhi  = p;  p += NN * NN;
    unsigned short* W1th = p;  p += NN * NN;
    unsigned short* W1tl = p;  p += NN * NN;
    unsigned short* W2th = p;  p += NN * NN;
    unsigned short* W2tl = p;  p += NN * NN;
    unsigned short* W2b  = p;  p += NN * NN;
    unsigned short* H1b  = p;  p += NN * NN;
    unsigned short* H1lo = p;  p += NN * NN;
    unsigned short* H2b  = p;  p += NN * NN;
    unsigned short* G2b  = p;  p += NN * NN;
    unsigned short* G1b  = p;  p += NN * NN;

    dim3 blk(256);
    prep <<<dim3(16, 16, 3), blk, 0, stream>>>(x, W1, W2, b3, xhi,
                                               W1th, W1tl, W2th, W2tl, W2b, out);
    fwd1 <<<dim3(16, 16), blk, 0, stream>>>(x, W1th, W1tl, b1, H1b, H1lo);
    fwd2 <<<dim3(16, 16), blk, 0, stream>>>(H1b, H1lo, W2th, W2tl, b2, w3,
                                            H2b, G2b, out);
    g1k  <<<dim3(16, 16), blk, 0, stream>>>(G2b, W2b, H1b, G1b);
    gramk<<<dim3(16, 16), blk, 0, stream>>>(xhi, H1b, G1b, H2b, G2b, gram);
}